// Round 6
// baseline (11266.772 us; speedup 1.0000x reference)
//
#include <hip/hip_runtime.h>
#include <math.h>

typedef unsigned short u16;
typedef unsigned long long u64;
typedef __attribute__((ext_vector_type(8))) short s16x8;
typedef __attribute__((ext_vector_type(4))) short s16x4;
typedef __attribute__((ext_vector_type(4))) float f4v;

__device__ __forceinline__ float bf2f(short u) {
    union { unsigned int i; float f; } v;
    v.i = ((unsigned int)(u16)u) << 16;
    return v.f;
}
__device__ __forceinline__ u16 f2bf(float f) {
    union { float f; unsigned int i; } v; v.f = f;
    unsigned int x = v.i;
    return (u16)((x + 0x7FFFu + ((x >> 16) & 1u)) >> 16);
}

// agent-scope (cross-XCD coherent, L2-bypassing) loads/stores
__device__ __forceinline__ u64 coh_load_u64(const u16* p) {
    return __hip_atomic_load((const u64*)p, __ATOMIC_RELAXED, __HIP_MEMORY_SCOPE_AGENT);
}
__device__ __forceinline__ void coh_store_u64(u16* p, u64 v) {
    __hip_atomic_store((u64*)p, v, __ATOMIC_RELAXED, __HIP_MEMORY_SCOPE_AGENT);
}
__device__ __forceinline__ unsigned flag_load(const unsigned* p) {
    return __hip_atomic_load(p, __ATOMIC_RELAXED, __HIP_MEMORY_SCOPE_AGENT);
}
__device__ __forceinline__ void flag_store(unsigned* p, unsigned v) {
    __hip_atomic_store(p, v, __ATOMIC_RELAXED, __HIP_MEMORY_SCOPE_AGENT);
}

__global__ void zero_bar(unsigned* p, int n) {
    int i = blockIdx.x * blockDim.x + threadIdx.x;
    if (i < n) p[i] = 0;
}

// ---------------- fp32 -> bf16 weight conversion (fallback path helper) ----------------
__global__ __launch_bounds__(256)
void cvt_bf16v(const float* __restrict__ src, u16* __restrict__ dst, int n4) {
    int i = blockIdx.x * 256 + threadIdx.x;
    int stride = gridDim.x * 256;
    for (; i < n4; i += stride) {
        f4v v = ((const f4v*)src)[i];
        s16x4 o;
#pragma unroll
        for (int j = 0; j < 4; ++j) o[j] = (short)f2bf(v[j]);
        ((s16x4*)dst)[i] = o;
    }
}

// ---------------- fp32 -> bf16 MFMA-fragment packing ----------------
// dst fragment f=(g*JT+jt)*KB+kb is 64 lanes x 8 bf16 contiguous (1 KB):
// lane l elem e -> row g*H+jt*16+(l&15), col kb*32+(l>>4)*8+e.
__global__ __launch_bounds__(256)
void cvt_pack(const float* __restrict__ src, u16* __restrict__ dst,
              int JT, int KB, int K)
{
    int fid = blockIdx.x * 4 + (threadIdx.x >> 6);
    int lane = threadIdx.x & 63;
    int nf = 3 * JT * KB;
    if (fid >= nf) return;
    int g = fid / (JT * KB);
    int rem = fid - g * JT * KB;
    int jt = rem / KB;
    int kb = rem - jt * KB;
    int j = jt * 16 + (lane & 15);
    int k = kb * 32 + (lane >> 4) * 8;
    const float* s = src + ((size_t)g * JT * 16 + j) * K + k;
    f4v a = *(const f4v*)s;
    f4v b = *(const f4v*)(s + 4);
    s16x8 o;
#pragma unroll
    for (int i = 0; i < 4; ++i) { o[i] = (short)f2bf(a[i]); o[4 + i] = (short)f2bf(b[i]); }
    *(s16x8*)(dst + (size_t)fid * 512 + lane * 8) = o;
}

// ---------------- layer0 input gates (one dir): xg = x @ W^T + bih, K=75 ----------------
__global__ __launch_bounds__(256)
void xg0_kernel(const float* __restrict__ x,   // [6400][75]
                const float* __restrict__ W,   // [3072][75] (this dir)
                const float* __restrict__ bih, // [3072]
                u16* __restrict__ xg)          // [6400][3072]
{
    const int bt0 = blockIdx.x * 16;
    __shared__ float xl[16][76];
    for (int idx = threadIdx.x; idx < 16 * 75; idx += 256) {
        int r = idx / 75, k = idx % 75;
        xl[r][k] = x[(size_t)(bt0 + r) * 75 + k];
    }
    __syncthreads();
    for (int i = 0; i < 12; ++i) {
        int g = threadIdx.x + i * 256;
        const float* wr = W + (size_t)g * 75;
        float bv = bih[g];
        float acc[16];
#pragma unroll
        for (int r = 0; r < 16; ++r) acc[r] = bv;
        for (int k = 0; k < 75; ++k) {
            float w = wr[k];
#pragma unroll
            for (int r = 0; r < 16; ++r) acc[r] += xl[r][k] * w;
        }
#pragma unroll
        for (int r = 0; r < 16; ++r)
            xg[(size_t)(bt0 + r) * 3072 + g] = f2bf(acc[r]);
    }
}

// ---------------- MFMA bt-GEMM: C[6400,3072] = A(bf16)[6400,K] @ B(fp32)[3072,K]^T + bias ----
// 128x64 tiles, XCD-aware mapping: XCD x owns n-tiles [6x,6x+6) for all m ->
// B slice (3 MB fp32) L2-resident per XCD; A panel streamed once per XCD.
__global__ __launch_bounds__(256)
void xg_gemm2(const u16* __restrict__ A, const float* __restrict__ Bm,
              const float* __restrict__ bias, u16* __restrict__ C, int K)
{
    __shared__ u16 Alds[128 * 40];
    __shared__ u16 Blds[64 * 40];
    const int bid = blockIdx.x;
    const int xcd = bid & 7;
    const int r = bid >> 3;                 // 0..299
    const int n_t = xcd * 6 + r % 6;        // 48 n-tiles
    const int m_t = r / 6;                  // 50 m-tiles
    const int m0 = m_t * 128;
    const int n0 = n_t * 64;
    const int tid = threadIdx.x;
    const int wv = tid >> 6;
    const int lane = tid & 63;
    const int kq = (lane >> 4) * 8;
    const int col = lane & 15;
    f4v acc[2][4];
#pragma unroll
    for (int am = 0; am < 2; ++am)
#pragma unroll
        for (int nt = 0; nt < 4; ++nt) acc[am][nt] = (f4v){0.f, 0.f, 0.f, 0.f};

    for (int k0 = 0; k0 < K; k0 += 32) {
#pragma unroll
        for (int i = 0; i < 2; ++i) {
            int c = tid * 2 + i;
            int row = c >> 2, kk = (c & 3) * 8;
            *(s16x8*)&Alds[row * 40 + kk] =
                *(const s16x8*)(A + (size_t)(m0 + row) * K + k0 + kk);
        }
        {
            int row = tid >> 2, kk = (tid & 3) * 8;
            f4v b0v = *(const f4v*)(Bm + (size_t)(n0 + row) * K + k0 + kk);
            f4v b1v = *(const f4v*)(Bm + (size_t)(n0 + row) * K + k0 + kk + 4);
            s16x8 bb;
#pragma unroll
            for (int i = 0; i < 4; ++i) { bb[i] = (short)f2bf(b0v[i]); bb[4 + i] = (short)f2bf(b1v[i]); }
            *(s16x8*)&Blds[row * 40 + kk] = bb;
        }
        __syncthreads();
        s16x8 a0 = *(const s16x8*)&Alds[(wv * 32 + (lane & 15)) * 40 + kq];
        s16x8 a1 = *(const s16x8*)&Alds[(wv * 32 + 16 + (lane & 15)) * 40 + kq];
#pragma unroll
        for (int nt = 0; nt < 4; ++nt) {
            s16x8 b = *(const s16x8*)&Blds[(nt * 16 + (lane & 15)) * 40 + kq];
            acc[0][nt] = __builtin_amdgcn_mfma_f32_16x16x32_bf16(a0, b, acc[0][nt], 0, 0, 0);
            acc[1][nt] = __builtin_amdgcn_mfma_f32_16x16x32_bf16(a1, b, acc[1][nt], 0, 0, 0);
        }
        __syncthreads();
    }
    const int rq = (lane >> 4) * 4;
#pragma unroll
    for (int am = 0; am < 2; ++am)
#pragma unroll
    for (int nt = 0; nt < 4; ++nt) {
        int n = n0 + nt * 16 + col;
        float bv = bias[n];
#pragma unroll
        for (int rg = 0; rg < 4; ++rg) {
            int m = m0 + wv * 32 + am * 16 + rq + rg;
            C[(size_t)m * 3072 + n] = f2bf(acc[am][nt][rg] + bv);
        }
    }
}

// ---------------- persistent encoder layer scan (one dir) ----------------
// 64 blocks x 256 threads = 16 jg x 4 bq. Sync group = same-bq (16 blocks).
// Producer-gated slice staging doubles as the barrier; batched dbuf weight pipeline.
__global__ __launch_bounds__(256)
void enc_persist(const u16* __restrict__ Wp,     // packed [3][64][32] frags (bf16)
                 const float* __restrict__ bias, // [2][3072] (bih,bhh) this dir
                 const u16* __restrict__ xg,     // [6400][3072] bf16 this dir
                 u16* __restrict__ hbf,          // [2][64][1024] bf16 ping-pong
                 u16* __restrict__ y,            // [6400][2048] bf16
                 int dir, unsigned* __restrict__ bar)
{
    __shared__ u16 Al[16 * 1024];                // 32 KB A-tile, XOR-swizzled
    __shared__ u16 OutE[16 * 64];                // 2 KB h-out staging
    const int tid = threadIdx.x;
    const int lane = tid & 63;
    const int wv = tid >> 6;
    const int xcd = blockIdx.x & 7;
    const int jg = xcd * 2 + ((blockIdx.x >> 3) & 1);  // 16 j-groups of 64
    const int bq = blockIdx.x >> 4;                    // 0..3
    const int b0 = bq * 16;
    unsigned* flags = bar + bq * 64;                   // 16 flags, idx = jg
    const int jc = jg * 64 + wv * 16 + (lane & 15);
    const int jt = jg * 4 + wv;
    const int kq = (lane >> 4) * 8;
    const int arow = lane & 15;
    const int axor = (arow & 7) << 3;
    const float bhr = bias[3072 + jc];
    const float bhz = bias[4096 + jc];
    const float bhn = bias[5120 + jc];
    const u16* pW[3];
    pW[0] = Wp + ((size_t)(0 * 64 + jt) * 32) * 512 + lane * 8;
    pW[1] = Wp + ((size_t)(1 * 64 + jt) * 32) * 512 + lane * 8;
    pW[2] = Wp + ((size_t)(2 * 64 + jt) * 32) * 512 + lane * 8;
    const int brow = b0 + (lane >> 4) * 4;
    const int srow = tid >> 4;        // staging row 0..15
    const int sci  = tid & 15;        // staging u64 idx 0..15 within 64-col slice
    f4v hold = {0.f, 0.f, 0.f, 0.f};

    for (int t = 0; t < 100; ++t) {
        f4v aR = {0.f, 0.f, 0.f, 0.f}, aZ = aR, aN = aR;
        if (t > 0) {
            const u16* hb = hbf + (size_t)(t & 1) * 65536 + (size_t)b0 * 1024;
            // own slice: guaranteed by own drain at prior sync
            {
                u64 v = coh_load_u64(hb + (size_t)srow * 1024 + jg * 64 + sci * 4);
                int c = srow * 128 + jg * 8 + (sci >> 1);
                int di = (c * 8) ^ ((srow & 7) << 3);
                *(u64*)&Al[di + (sci & 1) * 4] = v;
            }
            unsigned pending = 0xFFFFu & ~(1u << jg);
            int spins = 0;
            while (pending) {
                unsigned fv = flag_load(&flags[lane & 15]);
                unsigned ready = (unsigned)__ballot(fv >= (unsigned)t) & 0xFFFFu;
                unsigned newly = ready & pending;
                if (newly) {
                    u64 v[16];
#pragma unroll
                    for (int p = 0; p < 16; ++p)
                        if (newly & (1u << p))
                            v[p] = coh_load_u64(hb + (size_t)srow * 1024 + p * 64 + sci * 4);
#pragma unroll
                    for (int p = 0; p < 16; ++p)
                        if (newly & (1u << p)) {
                            int c = srow * 128 + p * 8 + (sci >> 1);
                            int di = (c * 8) ^ ((srow & 7) << 3);
                            *(u64*)&Al[di + (sci & 1) * 4] = v[p];
                        }
                    pending &= ~newly;
                }
                if (pending) {
                    __builtin_amdgcn_s_sleep(1);
                    if (++spins > (1 << 20)) break;    // bail-out
                }
            }
            __syncthreads();
            // batched double-buffered k-loop: 8 batches of 4 kb
            const int abase = arow * 1024 + kq;
            s16x8 W[2][3][4];
#pragma unroll
            for (int g = 0; g < 3; ++g)
#pragma unroll
                for (int q = 0; q < 4; ++q)
                    W[0][g][q] = *(const s16x8*)(pW[g] + (size_t)q * 512);
#pragma unroll
            for (int bt = 0; bt < 8; ++bt) {
                if (bt < 7) {
#pragma unroll
                    for (int g = 0; g < 3; ++g)
#pragma unroll
                        for (int q = 0; q < 4; ++q)
                            W[(bt + 1) & 1][g][q] =
                                *(const s16x8*)(pW[g] + (size_t)((bt + 1) * 4 + q) * 512);
                }
#pragma unroll
                for (int q = 0; q < 4; ++q) {
                    s16x8 av = *(const s16x8*)&Al[(abase + (bt * 4 + q) * 32) ^ axor];
                    aR = __builtin_amdgcn_mfma_f32_16x16x32_bf16(av, W[bt & 1][0][q], aR, 0, 0, 0);
                    aZ = __builtin_amdgcn_mfma_f32_16x16x32_bf16(av, W[bt & 1][1][q], aZ, 0, 0, 0);
                    aN = __builtin_amdgcn_mfma_f32_16x16x32_bf16(av, W[bt & 1][2][q], aN, 0, 0, 0);
                }
            }
        }
#pragma unroll
        for (int r = 0; r < 4; ++r) {
            int b = brow + r;
            const u16* xr = xg + ((size_t)b * 100 + t) * 3072;
            float pr = bf2f((short)xr[jc]) + aR[r] + bhr;
            float pz = bf2f((short)xr[1024 + jc]) + aZ[r] + bhz;
            float pn = bf2f((short)xr[2048 + jc]);
            float rg = 1.f / (1.f + expf(-pr));
            float zg = 1.f / (1.f + expf(-pz));
            float ng = tanhf(pn + rg * (aN[r] + bhn));
            float hnew = (1.f - zg) * ng + zg * hold[r];
            hold[r] = hnew;
            OutE[((lane >> 4) * 4 + r) * 64 + wv * 16 + (lane & 15)] = f2bf(hnew);
        }
        __syncthreads();
        if (tid < 128) {     // coalesced cross-block + y stores (16 b x 64 j tile)
            int bl = tid >> 3, jl = (tid & 7) * 8;
            s16x8 v = *(const s16x8*)&OutE[bl * 64 + jl];
            const u64* pv = (const u64*)&v;
            u16* hw = hbf + (size_t)((t + 1) & 1) * 65536
                    + (size_t)(b0 + bl) * 1024 + jg * 64 + jl;
            coh_store_u64(hw, pv[0]);
            coh_store_u64(hw + 4, pv[1]);
            *(s16x8*)(y + ((size_t)(b0 + bl) * 100 + t) * 2048
                        + (size_t)dir * 1024 + jg * 64 + jl) = v;
        }
        if (t < 99) {
            __syncthreads();                           // drain h stores (vmcnt 0)
            if (tid == 0) flag_store(&flags[jg], (unsigned)(t + 1));
        }
    }
}

// ---------------- persistent decoder scan, H=K=2048 ----------------
// 128 blocks x 256 threads = 32 jg x 4 bq. Sync group = same-bq (32 blocks).
__global__ __launch_bounds__(256)
void dec_persist(const u16* __restrict__ Wp,    // packed [3][128][64] frags (bf16)
                 const float* __restrict__ db,  // [2][6144] fp32
                 const float* __restrict__ h32, // [64][2048] fp32 init (pp0)
                 u16* __restrict__ hbf,         // [2][64][2048] bf16 ping-pong
                 u16* __restrict__ ys,          // [6400][2048] bf16
                 unsigned* __restrict__ bar)
{
    __shared__ u16 Al[16 * 2048];                // 64 KB A-tile, XOR-swizzled
    __shared__ u16 OutD[16 * 64];                // 2 KB h-out staging
    const int tid = threadIdx.x;
    const int lane = tid & 63;
    const int wv = tid >> 6;
    const int xcd = blockIdx.x & 7;
    const int idx = blockIdx.x >> 3;                   // 0..15
    const int jg = xcd * 4 + (idx & 3);                // 32 j-groups of 64
    const int bq = idx >> 2;                           // 0..3
    const int b0 = bq * 16;
    unsigned* flags = bar + bq * 64;                   // 32 flags, idx = jg
    const int jc = jg * 64 + wv * 16 + (lane & 15);
    const int jt = jg * 4 + wv;
    const int kq = (lane >> 4) * 8;
    const int arow = lane & 15;
    const int axor = (arow & 7) << 3;
    const float gir = db[jc]        + db[6144 + jc];
    const float giz = db[2048 + jc] + db[8192 + jc];
    const float gin = db[4096 + jc];
    const float bhn = db[10240 + jc];
    const u16* pW[3];
    pW[0] = Wp + ((size_t)(0 * 128 + jt) * 64) * 512 + lane * 8;
    pW[1] = Wp + ((size_t)(1 * 128 + jt) * 64) * 512 + lane * 8;
    pW[2] = Wp + ((size_t)(2 * 128 + jt) * 64) * 512 + lane * 8;
    const int srow = tid >> 4;
    const int sci  = tid & 15;
    f4v hold;
#pragma unroll
    for (int r = 0; r < 4; ++r)
        hold[r] = h32[(size_t)(b0 + (lane >> 4) * 4 + r) * 2048 + jc];

    for (int t = 0; t < 100; ++t) {
        const u16* hb = hbf + (size_t)(t & 1) * 131072 + (size_t)b0 * 2048;
        if (t == 0) {
            // unconditional full stage (gather-produced pp0), 32-deep burst
            u64 v[32];
#pragma unroll
            for (int p = 0; p < 32; ++p)
                v[p] = coh_load_u64(hb + (size_t)srow * 2048 + p * 64 + sci * 4);
#pragma unroll
            for (int p = 0; p < 32; ++p) {
                int c = srow * 256 + p * 8 + (sci >> 1);
                int di = (c * 8) ^ ((srow & 7) << 3);
                *(u64*)&Al[di + (sci & 1) * 4] = v[p];
            }
        } else {
            {   // own slice
                u64 v = coh_load_u64(hb + (size_t)srow * 2048 + jg * 64 + sci * 4);
                int c = srow * 256 + jg * 8 + (sci >> 1);
                int di = (c * 8) ^ ((srow & 7) << 3);
                *(u64*)&Al[di + (sci & 1) * 4] = v;
            }
            unsigned pending = 0xFFFFFFFFu & ~(1u << jg);
            int spins = 0;
            while (pending) {
                unsigned fv = flag_load(&flags[lane & 31]);
                unsigned ready = (unsigned)__ballot(fv >= (unsigned)t);
                unsigned newly = ready & pending;
                if (newly) {
                    u64 v[32];
#pragma unroll
                    for (int p = 0; p < 32; ++p)
                        if (newly & (1u << p))
                            v[p] = coh_load_u64(hb + (size_t)srow * 2048 + p * 64 + sci * 4);
#pragma unroll
                    for (int p = 0; p < 32; ++p)
                        if (newly & (1u << p)) {
                            int c = srow * 256 + p * 8 + (sci >> 1);
                            int di = (c * 8) ^ ((srow & 7) << 3);
                            *(u64*)&Al[di + (sci & 1) * 4] = v[p];
                        }
                    pending &= ~newly;
                }
                if (pending) {
                    __builtin_amdgcn_s_sleep(1);
                    if (++spins > (1 << 20)) break;    // bail-out
                }
            }
        }
        __syncthreads();
        f4v aR = {0.f, 0.f, 0.f, 0.f}, aZ = aR, aN = aR;
        const int abase = arow * 2048 + kq;
        s16x8 W[2][3][4];
#pragma unroll
        for (int g = 0; g < 3; ++g)
#pragma unroll
            for (int q = 0; q < 4; ++q)
                W[0][g][q] = *(const s16x8*)(pW[g] + (size_t)q * 512);
#pragma unroll
        for (int bt = 0; bt < 16; ++bt) {
            if (bt < 15) {
#pragma unroll
                for (int g = 0; g < 3; ++g)
#pragma unroll
                    for (int q = 0; q < 4; ++q)
                        W[(bt + 1) & 1][g][q] =
                            *(const s16x8*)(pW[g] + (size_t)((bt + 1) * 4 + q) * 512);
            }
#pragma unroll
            for (int q = 0; q < 4; ++q) {
                s16x8 av = *(const s16x8*)&Al[(abase + (bt * 4 + q) * 32) ^ axor];
                aR = __builtin_amdgcn_mfma_f32_16x16x32_bf16(av, W[bt & 1][0][q], aR, 0, 0, 0);
                aZ = __builtin_amdgcn_mfma_f32_16x16x32_bf16(av, W[bt & 1][1][q], aZ, 0, 0, 0);
                aN = __builtin_amdgcn_mfma_f32_16x16x32_bf16(av, W[bt & 1][2][q], aN, 0, 0, 0);
            }
        }
        __syncthreads();     // Al reads done before next staging; OutD reuse safe
#pragma unroll
        for (int r = 0; r < 4; ++r) {
            float pr = gir + aR[r];
            float pz = giz + aZ[r];
            float rg = 1.f / (1.f + expf(-pr));
            float zg = 1.f / (1.f + expf(-pz));
            float ng = tanhf(gin + rg * (aN[r] + bhn));
            float hnew = (1.f - zg) * ng + zg * hold[r];
            hold[r] = hnew;
            OutD[((lane >> 4) * 4 + r) * 64 + wv * 16 + (lane & 15)] = f2bf(hnew);
        }
        __syncthreads();
        if (tid < 128) {     // coalesced cross-block + ys stores (16 b x 64 j tile)
            int bl = tid >> 3, jl = (tid & 7) * 8;
            s16x8 v = *(const s16x8*)&OutD[bl * 64 + jl];
            const u64* pv = (const u64*)&v;
            u16* hw = hbf + (size_t)((t + 1) & 1) * 131072
                    + (size_t)(b0 + bl) * 2048 + jg * 64 + jl;
            coh_store_u64(hw, pv[0]);
            coh_store_u64(hw + 4, pv[1]);
            *(s16x8*)(ys + ((size_t)(b0 + bl) * 100 + t) * 2048 + jg * 64 + jl) = v;
        }
        if (t < 99) {
            __syncthreads();                           // drain h stores
            if (tid == 0) flag_store(&flags[jg], (unsigned)(t + 1));
        }
    }
}

// ---------------- gather enc_hidden = y[b, sl-1]; init decoder h ----------------
__global__ __launch_bounds__(256)
void gather_kernel(const int* __restrict__ seq_len, const u16* __restrict__ y,
                   float* __restrict__ out_enc, float* __restrict__ h32d,
                   u16* __restrict__ hbfd)
{
    int idx = blockIdx.x * 256 + threadIdx.x;   // < 131072
    int b = idx >> 11, j = idx & 2047;
    int s = seq_len[b];
    s = s < 1 ? 1 : (s > 100 ? 100 : s);
    u16 v = y[((size_t)b * 100 + (s - 1)) * 2048 + j];
    float f = bf2f((short)v);
    out_enc[idx] = f;
    h32d[idx] = f;     // pp0
    hbfd[idx] = v;     // pp0
}

// ---------------- output projection: dec_out[6400,75] = ys @ out_W^T + out_b ----------------
__global__ __launch_bounds__(256)
void proj_kernel(const u16* __restrict__ ys, const float* __restrict__ oW,
                 const float* __restrict__ oB, float* __restrict__ dec_out)
{
    const int r0 = blockIdx.x * 8;   // 800 blocks
    __shared__ float yl[8][2048];
    __shared__ float psum[3][8][76];
    for (int idx = threadIdx.x; idx < 2048; idx += 256) {
        int rr = idx >> 8, cc = idx & 255;
        s16x8 v = ((const s16x8*)(ys + (size_t)(r0 + rr) * 2048))[cc];
#pragma unroll
        for (int i = 0; i < 8; ++i) yl[rr][cc * 8 + i] = bf2f(v[i]);
    }
    __syncthreads();
    if (threadIdx.x < 225) {
        int d = threadIdx.x % 75, seg = threadIdx.x / 75;
        int ks = seg * 683, ke = ks + 683 < 2048 ? ks + 683 : 2048;
        const float* wr = oW + (size_t)d * 2048;
        float acc[8] = {0.f, 0.f, 0.f, 0.f, 0.f, 0.f, 0.f, 0.f};
        for (int k = ks; k < ke; ++k) {
            float w = wr[k];
#pragma unroll
            for (int r = 0; r < 8; ++r) acc[r] += yl[r][k] * w;
        }
#pragma unroll
        for (int r = 0; r < 8; ++r) psum[seg][r][d] = acc[r];
    }
    __syncthreads();
    for (int idx = threadIdx.x; idx < 600; idx += 256) {
        int r = idx / 75, d = idx % 75;
        dec_out[(size_t)(r0 + r) * 75 + d] =
            psum[0][r][d] + psum[1][r][d] + psum[2][r][d] + oB[d];
    }
}

// ================== fallback kernels (small-ws path) ==================
__device__ __forceinline__ void gemv3_f32(const float* __restrict__ w0,
                                          const float* __restrict__ w1,
                                          const float* __restrict__ w2,
                                          const f4v* __restrict__ hv,
                                          int n4, float& a0, float& a1, float& a2)
{
    for (int k = 0; k < n4; ++k) {
        f4v h4 = hv[k];
        f4v x0 = *(const f4v*)(w0 + k * 4);
        f4v x1 = *(const f4v*)(w1 + k * 4);
        f4v x2 = *(const f4v*)(w2 + k * 4);
        a0 += h4[0]*x0[0] + h4[1]*x0[1] + h4[2]*x0[2] + h4[3]*x0[3];
        a1 += h4[0]*x1[0] + h4[1]*x1[1] + h4[2]*x1[2] + h4[3]*x1[3];
        a2 += h4[0]*x2[0] + h4[1]*x2[1] + h4[2]*x2[2] + h4[3]*x2[3];
    }
}
__device__ __forceinline__ float dot_w32_v32(const float* __restrict__ w,
                                             const float* __restrict__ v, int n)
{
    float a = 0.f;
    for (int k = 0; k < n; ++k) a += w[k] * v[k];
    return a;
}
__device__ __forceinline__ float dot_w32_vbf(const float* __restrict__ w,
                                             const u16* __restrict__ v, int n8)
{
    float a = 0.f;
    for (int k8 = 0; k8 < n8; ++k8) {
        s16x8 v8 = *(const s16x8*)(v + k8 * 8);
        f4v w0 = *(const f4v*)(w + k8 * 8);
        f4v w1 = *(const f4v*)(w + k8 * 8 + 4);
        a += w0[0]*bf2f(v8[0]) + w0[1]*bf2f(v8[1]) + w0[2]*bf2f(v8[2]) + w0[3]*bf2f(v8[3])
           + w1[0]*bf2f(v8[4]) + w1[1]*bf2f(v8[5]) + w1[2]*bf2f(v8[6]) + w1[7 - 3]*bf2f(v8[7]);
    }
    return a;
}

__global__ __launch_bounds__(512)
void enc_scan_fused(int t,
                    const float* __restrict__ h_in, float* __restrict__ h_out,
                    const float* __restrict__ Whh, size_t whh_stride,
                    const float* __restrict__ Wih, size_t wih_stride, int Kin,
                    const float* __restrict__ xf, const u16* __restrict__ xb,
                    const float* __restrict__ bias, int bias_stride,
                    u16* __restrict__ y)
{
    const int dir = blockIdx.z;
    const int jt = blockIdx.x;
    const int b0 = blockIdx.y * 16;
    __shared__ float hlds[16][1024];
    const float* hin = h_in + (size_t)dir * 65536 + (size_t)b0 * 1024;
    if (t == 0) {
        f4v z = {0.f, 0.f, 0.f, 0.f};
        for (int idx = threadIdx.x; idx < 4096; idx += 512) ((f4v*)hlds)[idx] = z;
    } else {
        for (int idx = threadIdx.x; idx < 4096; idx += 512)
            ((f4v*)hlds)[idx] = ((const f4v*)hin)[idx];
    }
    __syncthreads();
    const int jl = threadIdx.x & 31;
    const int j  = jt * 32 + jl;
    const int bp = threadIdx.x >> 5;
    const float* wd = Whh + (size_t)dir * whh_stride;
    float a0 = 0.f, a1 = 0.f, a2 = 0.f;
    gemv3_f32(wd + (size_t)j * 1024, wd + (size_t)(1024 + j) * 1024,
              wd + (size_t)(2048 + j) * 1024, (const f4v*)&hlds[bp][0], 256, a0, a1, a2);
    const float* bd = bias + dir * bias_stride;
    const float* wi = Wih + (size_t)dir * wih_stride;
    const int gb = b0 + bp;
    float gi[3];
#pragma unroll
    for (int g = 0; g < 3; ++g) {
        const float* wr = wi + (size_t)(g * 1024 + j) * Kin;
        float s;
        if (xf) s = dot_w32_v32(wr, xf + ((size_t)gb * 100 + t) * Kin, Kin);
        else    s = dot_w32_vbf(wr, xb + ((size_t)gb * 100 + t) * Kin, Kin >> 3);
        gi[g] = bd[g * 1024 + j] + s;
    }
    const float* bhh = bd + 3072;
    float pr = gi[0] + a0 + bhh[j];
    float pz = gi[1] + a1 + bhh[1024 + j];
    float rg = 1.f / (1.f + expf(-pr));
    float zg = 1.f / (1.f + expf(-pz));
    float ng = tanhf(gi[2] + rg * (a2 + bhh[2048 + j]));
    float hold = hlds[bp][j];
    float hnew = (1.f - zg) * ng + zg * hold;
    h_out[(size_t)dir * 65536 + (size_t)gb * 1024 + j] = hnew;
    y[((size_t)gb * 100 + t) * 2048 + (size_t)dir * 1024 + j] = f2bf(hnew);
}

__global__ __launch_bounds__(512)
void dec_scan_step(int t, const float* __restrict__ h_in, float* __restrict__ h_out,
                   const float* __restrict__ Whh, const float* __restrict__ db,
                   u16* __restrict__ ys)
{
    const int jt = blockIdx.x;
    const int b0 = blockIdx.y * 16;
    __shared__ float hlds[16][1024];
    const int jl = threadIdx.x & 31;
    const int j  = jt * 32 + jl;
    const int bp = threadIdx.x >> 5;
    float a0 = 0.f, a1 = 0.f, a2 = 0.f;
    float hold = 0.f;
    for (int kc = 0; kc < 2; ++kc) {
        for (int idx = threadIdx.x; idx < 4096; idx += 512) {
            int rr = idx >> 8, cc = idx & 255;
            ((f4v*)hlds)[idx] = *(const f4v*)(h_in + (size_t)(b0 + rr) * 2048 + kc * 1024 + cc * 4);
        }
        __syncthreads();
        if ((j >> 10) == kc) hold = hlds[bp][j & 1023];
        const float* wb = Whh + kc * 1024;
        gemv3_f32(wb + (size_t)j * 2048, wb + (size_t)(2048 + j) * 2048,
                  wb + (size_t)(4096 + j) * 2048, (const f4v*)&hlds[bp][0], 256, a0, a1, a2);
        __syncthreads();
    }
    const int gb = b0 + bp;
    float pr = db[j] + a0 + db[6144 + j];
    float pz = db[2048 + j] + a1 + db[6144 + 2048 + j];
    float rg = 1.f / (1.f + expf(-pr));
    float zg = 1.f / (1.f + expf(-pz));
    float ng = tanhf(db[4096 + j] + rg * (a2 + db[6144 + 4096 + j]));
    float hnew = (1.f - zg) * ng + zg * hold;
    h_out[(size_t)gb * 2048 + j] = hnew;
    ys[((size_t)gb * 100 + t) * 2048 + j] = f2bf(hnew);
}

// ============================ launcher ============================
extern "C" void kernel_launch(void* const* d_in, const int* in_sizes, int n_in,
                              void* d_out, int out_size, void* d_ws, size_t ws_size,
                              hipStream_t stream)
{
    const float* x    = (const float*)d_in[0];
    const int*   sl   = (const int*)d_in[1];
    const float* Wih0 = (const float*)d_in[2];
    const float* Whh0 = (const float*)d_in[3];
    const float* b0   = (const float*)d_in[4];
    const float* Wih  = (const float*)d_in[5];
    const float* Whh  = (const float*)d_in[6];
    const float* bE   = (const float*)d_in[7];
    const float* dWhh = (const float*)d_in[9];
    const float* dB   = (const float*)d_in[10];
    const float* oW   = (const float*)d_in[11];
    const float* oB   = (const float*)d_in[12];
    float* out_enc = (float*)d_out;            // [64][2048]
    float* dec_out = (float*)d_out + 131072;   // [64][100][75]

    char* ws = (char*)d_ws;
    // ---- persistent-path layout ----
    const size_t XG_OFF   = 0;            // [6400][3072] bf16 (one dir): 39,321,600
    const size_t YA_OFF   = 39321600;     // [6400][2048] bf16: 26,214,400
    const size_t YB_OFF   = 65536000;     // [6400][2048] bf16
    const size_t WC_OFF   = 91750400;     // packed enc W bf16: 6,291,456
    const size_t HBFE_OFF = 98566144;     // [2][64][1024] bf16: 262,144
    const size_t H32D_OFF = 98828288;     // [2][64][2048] f32: 1,048,576
    const size_t HBFD_OFF = 99876864;     // [2][64][2048] bf16: 524,288
    const size_t BAR_OFF  = 100401152;    // 7 slots x 1 KB
    const size_t NEED     = 100408320;

    dim3 blk256(256), blk512(512);

    if (ws_size >= NEED) {
        u16*   xg   = (u16*)(ws + XG_OFF);
        u16*   y_a  = (u16*)(ws + YA_OFF);
        u16*   y_b  = (u16*)(ws + YB_OFF);
        u16*   Wc   = (u16*)(ws + WC_OFF);
        u16*   hbfE = (u16*)(ws + HBFE_OFF);
        float* h32D = (float*)(ws + H32D_OFF);
        u16*   hbfD = (u16*)(ws + HBFD_OFF);
        unsigned* bar = (unsigned*)(ws + BAR_OFF);

        zero_bar<<<dim3(7), blk256, 0, stream>>>(bar, 1792);

        int slot = 0;
        for (int l = 0; l < 3; ++l) {
            const u16* y_in = (l == 0) ? (const u16*)0 : ((l == 1) ? y_a : y_b);
            u16* y_out      = (l == 2) ? y_a : ((l == 0) ? y_a : y_b);
            for (int d = 0; d < 2; ++d) {
                const float* Wsrc = (l == 0) ? (Whh0 + (size_t)d * 3145728)
                                             : (Whh + ((size_t)(l - 1) * 2 + d) * 3145728);
                const float* bias = (l == 0) ? (b0 + (size_t)d * 6144)
                                             : (bE + (size_t)(l - 1) * 12288 + (size_t)d * 6144);
                cvt_pack<<<dim3(1536), blk256, 0, stream>>>(Wsrc, Wc, 64, 32, 1024);
                if (l == 0)
                    xg0_kernel<<<dim3(400), blk256, 0, stream>>>(
                        x, Wih0 + (size_t)d * 230400, b0 + (size_t)d * 6144, xg);
                else
                    xg_gemm2<<<dim3(2400), blk256, 0, stream>>>(
                        y_in, Wih + ((size_t)(l - 1) * 2 + d) * 6291456, bias, xg, 2048);
                enc_persist<<<dim3(64), blk256, 0, stream>>>(
                    Wc, bias, xg, hbfE, y_out, d, bar + (size_t)slot * 256);
                ++slot;
            }
        }
        gather_kernel<<<dim3(512), blk256, 0, stream>>>(sl, y_a, out_enc, h32D, hbfD);
        u16* decW = (u16*)(ws + XG_OFF);   // reuse xg region (25.2 MB needed)
        cvt_pack<<<dim3(6144), blk256, 0, stream>>>(dWhh, decW, 128, 64, 2048);
        dec_persist<<<dim3(128), blk256, 0, stream>>>(decW, dB, h32D, hbfD, y_b,
                                                      bar + (size_t)6 * 256);
        proj_kernel<<<dim3(800), blk256, 0, stream>>>(y_b, oW, oB, dec_out);
    } else {
        // ---- fallback: fused path (~55 MiB) ----
        const size_t Y_B = 26214400;
        u16*   y_a  = (u16*)ws;
        u16*   y_b  = (u16*)(ws + Y_B);
        float* hE   = (float*)(ws + 2 * Y_B);                 // [2][2][64][1024] f32: 1 MB
        float* h32D = (float*)(ws + 2 * Y_B + 1048576);       // [2][64][2048] f32: 1 MB
        u16*   hbfD = (u16*)(ws + 2 * Y_B + 2097152);         // 0.5 MB

        for (int t = 0; t < 100; ++t) {
            int pp = t & 1;
            enc_scan_fused<<<dim3(32, 4, 2), blk512, 0, stream>>>(
                t, hE + (size_t)pp * 131072, hE + (size_t)(pp ^ 1) * 131072,
                Whh0, (size_t)3145728, Wih0, (size_t)230400, 75, x, (const u16*)0,
                b0, 6144, y_a);
        }
        for (int l = 0; l < 2; ++l) {
            const u16* yin = (l == 0) ? y_a : y_b;
            u16* yout      = (l == 0) ? y_b : y_a;
            for (int t = 0; t < 100; ++t) {
                int pp = t & 1;
                enc_scan_fused<<<dim3(32, 4, 2), blk512, 0, stream>>>(
                    t, hE + (size_t)pp * 131072, hE + (size_t)(pp ^ 1) * 131072,
                    Whh + (size_t)l * 2 * 3145728, (size_t)3145728,
                    Wih + (size_t)l * 2 * 6291456, (size_t)6291456, 2048,
                    (const float*)0, yin, bE + (size_t)l * 12288, 6144, yout);
            }
        }
        gather_kernel<<<dim3(512), blk256, 0, stream>>>(sl, y_a, out_enc, h32D, hbfD);
        for (int t = 0; t < 100; ++t) {
            int pp = t & 1;
            dec_scan_step<<<dim3(64, 4), blk512, 0, stream>>>(
                t, h32D + (size_t)pp * 131072, h32D + (size_t)(pp ^ 1) * 131072, dWhh, dB, y_b);
        }
        proj_kernel<<<dim3(800), blk256, 0, stream>>>(y_b, oW, oB, dec_out);
    }
}

// Round 9
// 7884.733 us; speedup vs baseline: 1.4289x; 1.4289x over previous
//
#include <hip/hip_runtime.h>
#include <math.h>

typedef unsigned short u16;
typedef unsigned long long u64;
typedef __attribute__((ext_vector_type(8))) short s16x8;
typedef __attribute__((ext_vector_type(4))) short s16x4;
typedef __attribute__((ext_vector_type(4))) float f4v;

__device__ __forceinline__ float bf2f(short u) {
    union { unsigned int i; float f; } v;
    v.i = ((unsigned int)(u16)u) << 16;
    return v.f;
}
__device__ __forceinline__ u16 f2bf(float f) {
    union { float f; unsigned int i; } v; v.f = f;
    unsigned int x = v.i;
    return (u16)((x + 0x7FFFu + ((x >> 16) & 1u)) >> 16);
}

// agent-scope (cross-XCD coherent, L2-bypassing) loads/stores
__device__ __forceinline__ u64 coh_load_u64(const u16* p) {
    return __hip_atomic_load((const u64*)p, __ATOMIC_RELAXED, __HIP_MEMORY_SCOPE_AGENT);
}
__device__ __forceinline__ void coh_store_u64(u16* p, u64 v) {
    __hip_atomic_store((u64*)p, v, __ATOMIC_RELAXED, __HIP_MEMORY_SCOPE_AGENT);
}
__device__ __forceinline__ unsigned flag_load(const unsigned* p) {
    return __hip_atomic_load(p, __ATOMIC_RELAXED, __HIP_MEMORY_SCOPE_AGENT);
}
__device__ __forceinline__ void flag_store(unsigned* p, unsigned v) {
    __hip_atomic_store(p, v, __ATOMIC_RELAXED, __HIP_MEMORY_SCOPE_AGENT);
}

// ---------------- flag-array grid barrier (no RMW; thread0-only epoch poll) ----------------
// slot = 256 u32 (1 KB): flags[0..nblk-1], epoch at [192]. Block 0 sweeps; others
// poll ONE epoch word -> minimal coherent-fabric traffic (R6 lesson: per-consumer
// flag-vector polling cost 3.3 GB of EA traffic and 3.6x dec slowdown).
__device__ __forceinline__ void flag_barrier(unsigned* slot, int nblk, unsigned tgt) {
    __syncthreads();                       // all waves' stores drained before flag
    if (threadIdx.x == 0)
        flag_store(&slot[blockIdx.x], tgt);
    if (blockIdx.x == 0 && (int)threadIdx.x < 64) {
        int spins = 0;
        for (;;) {
            int ok = 1;
            for (int i = (int)threadIdx.x; i < nblk; i += 64)
                ok &= (flag_load(&slot[i]) >= tgt);
            if (__all(ok)) break;
            __builtin_amdgcn_s_sleep(2);
            if (++spins > (1 << 20)) break;     // bail-out
        }
        if (threadIdx.x == 0)
            flag_store(&slot[192], tgt);
    }
    if (threadIdx.x == 0) {
        int spins2 = 0;
        while (flag_load(&slot[192]) < tgt) {
            __builtin_amdgcn_s_sleep(1);
            if (++spins2 > (1 << 20)) break;    // bail-out
        }
    }
    __syncthreads();
    asm volatile("" ::: "memory");
}

__global__ void zero_bar(unsigned* p, int n) {
    int i = blockIdx.x * blockDim.x + threadIdx.x;
    if (i < n) p[i] = 0;
}

// ---------------- fp32 -> bf16 weight conversion (fallback path helper) ----------------
__global__ __launch_bounds__(256)
void cvt_bf16v(const float* __restrict__ src, u16* __restrict__ dst, int n4) {
    int i = blockIdx.x * 256 + threadIdx.x;
    int stride = gridDim.x * 256;
    for (; i < n4; i += stride) {
        f4v v = ((const f4v*)src)[i];
        s16x4 o;
#pragma unroll
        for (int j = 0; j < 4; ++j) o[j] = (short)f2bf(v[j]);
        ((s16x4*)dst)[i] = o;
    }
}

// ---------------- fp32 -> bf16 MFMA-fragment packing ----------------
// dst fragment f=(g*JT+jt)*KB+kb is 64 lanes x 8 bf16 contiguous (1 KB):
// lane l elem e -> row g*H+jt*16+(l&15), col kb*32+(l>>4)*8+e.
__global__ __launch_bounds__(256)
void cvt_pack(const float* __restrict__ src, u16* __restrict__ dst,
              int JT, int KB, int K)
{
    int fid = blockIdx.x * 4 + (threadIdx.x >> 6);
    int lane = threadIdx.x & 63;
    int nf = 3 * JT * KB;
    if (fid >= nf) return;
    int g = fid / (JT * KB);
    int rem = fid - g * JT * KB;
    int jt = rem / KB;
    int kb = rem - jt * KB;
    int j = jt * 16 + (lane & 15);
    int k = kb * 32 + (lane >> 4) * 8;
    const float* s = src + ((size_t)g * JT * 16 + j) * K + k;
    f4v a = *(const f4v*)s;
    f4v b = *(const f4v*)(s + 4);
    s16x8 o;
#pragma unroll
    for (int i = 0; i < 4; ++i) { o[i] = (short)f2bf(a[i]); o[4 + i] = (short)f2bf(b[i]); }
    *(s16x8*)(dst + (size_t)fid * 512 + lane * 8) = o;
}

// ---------------- layer0 input gates (one dir): xg = x @ W^T + bih, K=75 ----------------
__global__ __launch_bounds__(256)
void xg0_kernel(const float* __restrict__ x,   // [6400][75]
                const float* __restrict__ W,   // [3072][75] (this dir)
                const float* __restrict__ bih, // [3072]
                u16* __restrict__ xg)          // [6400][3072]
{
    const int bt0 = blockIdx.x * 16;
    __shared__ float xl[16][76];
    for (int idx = threadIdx.x; idx < 16 * 75; idx += 256) {
        int r = idx / 75, k = idx % 75;
        xl[r][k] = x[(size_t)(bt0 + r) * 75 + k];
    }
    __syncthreads();
    for (int i = 0; i < 12; ++i) {
        int g = threadIdx.x + i * 256;
        const float* wr = W + (size_t)g * 75;
        float bv = bih[g];
        float acc[16];
#pragma unroll
        for (int r = 0; r < 16; ++r) acc[r] = bv;
        for (int k = 0; k < 75; ++k) {
            float w = wr[k];
#pragma unroll
            for (int r = 0; r < 16; ++r) acc[r] += xl[r][k] * w;
        }
#pragma unroll
        for (int r = 0; r < 16; ++r)
            xg[(size_t)(bt0 + r) * 3072 + g] = f2bf(acc[r]);
    }
}

// ---------------- MFMA bt-GEMM: C[6400,3072] = A(bf16)[6400,K] @ B(fp32)[3072,K]^T + bias ----
// 128x64 tiles, XCD-aware mapping: XCD x owns n-tiles [6x,6x+6) for all m ->
// B slice (3 MB fp32) L2-resident per XCD; A panel streamed once per XCD.
__global__ __launch_bounds__(256)
void xg_gemm2(const u16* __restrict__ A, const float* __restrict__ Bm,
              const float* __restrict__ bias, u16* __restrict__ C, int K)
{
    __shared__ u16 Alds[128 * 40];
    __shared__ u16 Blds[64 * 40];
    const int bid = blockIdx.x;
    const int xcd = bid & 7;
    const int r = bid >> 3;                 // 0..299
    const int n_t = xcd * 6 + r % 6;        // 48 n-tiles
    const int m_t = r / 6;                  // 50 m-tiles
    const int m0 = m_t * 128;
    const int n0 = n_t * 64;
    const int tid = threadIdx.x;
    const int wv = tid >> 6;
    const int lane = tid & 63;
    const int kq = (lane >> 4) * 8;
    const int col = lane & 15;
    f4v acc[2][4];
#pragma unroll
    for (int am = 0; am < 2; ++am)
#pragma unroll
        for (int nt = 0; nt < 4; ++nt) acc[am][nt] = (f4v){0.f, 0.f, 0.f, 0.f};

    for (int k0 = 0; k0 < K; k0 += 32) {
#pragma unroll
        for (int i = 0; i < 2; ++i) {
            int c = tid * 2 + i;
            int row = c >> 2, kk = (c & 3) * 8;
            *(s16x8*)&Alds[row * 40 + kk] =
                *(const s16x8*)(A + (size_t)(m0 + row) * K + k0 + kk);
        }
        {
            int row = tid >> 2, kk = (tid & 3) * 8;
            f4v b0v = *(const f4v*)(Bm + (size_t)(n0 + row) * K + k0 + kk);
            f4v b1v = *(const f4v*)(Bm + (size_t)(n0 + row) * K + k0 + kk + 4);
            s16x8 bb;
#pragma unroll
            for (int i = 0; i < 4; ++i) { bb[i] = (short)f2bf(b0v[i]); bb[4 + i] = (short)f2bf(b1v[i]); }
            *(s16x8*)&Blds[row * 40 + kk] = bb;
        }
        __syncthreads();
        s16x8 a0 = *(const s16x8*)&Alds[(wv * 32 + (lane & 15)) * 40 + kq];
        s16x8 a1 = *(const s16x8*)&Alds[(wv * 32 + 16 + (lane & 15)) * 40 + kq];
#pragma unroll
        for (int nt = 0; nt < 4; ++nt) {
            s16x8 b = *(const s16x8*)&Blds[(nt * 16 + (lane & 15)) * 40 + kq];
            acc[0][nt] = __builtin_amdgcn_mfma_f32_16x16x32_bf16(a0, b, acc[0][nt], 0, 0, 0);
            acc[1][nt] = __builtin_amdgcn_mfma_f32_16x16x32_bf16(a1, b, acc[1][nt], 0, 0, 0);
        }
        __syncthreads();
    }
    const int rq = (lane >> 4) * 4;
#pragma unroll
    for (int am = 0; am < 2; ++am)
#pragma unroll
    for (int nt = 0; nt < 4; ++nt) {
        int n = n0 + nt * 16 + col;
        float bv = bias[n];
#pragma unroll
        for (int rg = 0; rg < 4; ++rg) {
            int m = m0 + wv * 32 + am * 16 + rq + rg;
            C[(size_t)m * 3072 + n] = f2bf(acc[am][nt][rg] + bv);
        }
    }
}

// ---------------- persistent encoder layer scan (one dir) ----------------
// 64 blocks x 256 threads = 16 jg x 4 bq. Sync group = same-bq (16 blocks).
// Producer-gated slice staging doubles as the barrier (low contention at 16 flags).
__global__ __launch_bounds__(256)
void enc_persist(const u16* __restrict__ Wp,     // packed [3][64][32] frags (bf16)
                 const float* __restrict__ bias, // [2][3072] (bih,bhh) this dir
                 const u16* __restrict__ xg,     // [6400][3072] bf16 this dir
                 u16* __restrict__ hbf,          // [2][64][1024] bf16 ping-pong
                 u16* __restrict__ y,            // [6400][2048] bf16
                 int dir, unsigned* __restrict__ bar)
{
    __shared__ u16 Al[16 * 1024];                // 32 KB A-tile, XOR-swizzled
    __shared__ u16 OutE[16 * 64];                // 2 KB h-out staging
    const int tid = threadIdx.x;
    const int lane = tid & 63;
    const int wv = tid >> 6;
    const int xcd = blockIdx.x & 7;
    const int jg = xcd * 2 + ((blockIdx.x >> 3) & 1);  // 16 j-groups of 64
    const int bq = blockIdx.x >> 4;                    // 0..3
    const int b0 = bq * 16;
    unsigned* flags = bar + bq * 64;                   // 16 flags, idx = jg
    const int jc = jg * 64 + wv * 16 + (lane & 15);
    const int jt = jg * 4 + wv;
    const int kq = (lane >> 4) * 8;
    const int arow = lane & 15;
    const int axor = (arow & 7) << 3;
    const float bhr = bias[3072 + jc];
    const float bhz = bias[4096 + jc];
    const float bhn = bias[5120 + jc];
    const u16* pW[3];
    pW[0] = Wp + ((size_t)(0 * 64 + jt) * 32) * 512 + lane * 8;
    pW[1] = Wp + ((size_t)(1 * 64 + jt) * 32) * 512 + lane * 8;
    pW[2] = Wp + ((size_t)(2 * 64 + jt) * 32) * 512 + lane * 8;
    const int brow = b0 + (lane >> 4) * 4;
    const int srow = tid >> 4;        // staging row 0..15
    const int sci  = tid & 15;        // staging u64 idx 0..15 within 64-col slice
    f4v hold = {0.f, 0.f, 0.f, 0.f};

    for (int t = 0; t < 100; ++t) {
        f4v aR = {0.f, 0.f, 0.f, 0.f}, aZ = aR, aN = aR;
        if (t > 0) {
            const u16* hb = hbf + (size_t)(t & 1) * 65536 + (size_t)b0 * 1024;
            // own slice: guaranteed by own drain at prior sync
            {
                u64 v = coh_load_u64(hb + (size_t)srow * 1024 + jg * 64 + sci * 4);
                int c = srow * 128 + jg * 8 + (sci >> 1);
                int di = (c * 8) ^ ((srow & 7) << 3);
                *(u64*)&Al[di + (sci & 1) * 4] = v;
            }
            unsigned pending = 0xFFFFu & ~(1u << jg);
            int spins = 0;
            while (pending) {
                unsigned fv = flag_load(&flags[lane & 15]);
                unsigned ready = (unsigned)__ballot(fv >= (unsigned)t) & 0xFFFFu;
                unsigned newly = ready & pending;
                if (newly) {
                    u64 v[16];
#pragma unroll
                    for (int p = 0; p < 16; ++p)
                        if (newly & (1u << p))
                            v[p] = coh_load_u64(hb + (size_t)srow * 1024 + p * 64 + sci * 4);
#pragma unroll
                    for (int p = 0; p < 16; ++p)
                        if (newly & (1u << p)) {
                            int c = srow * 128 + p * 8 + (sci >> 1);
                            int di = (c * 8) ^ ((srow & 7) << 3);
                            *(u64*)&Al[di + (sci & 1) * 4] = v[p];
                        }
                    pending &= ~newly;
                }
                if (pending) {
                    __builtin_amdgcn_s_sleep(1);
                    if (++spins > (1 << 20)) break;    // bail-out
                }
            }
            __syncthreads();
            // batched double-buffered k-loop: 8 batches of 4 kb
            const int abase = arow * 1024 + kq;
            s16x8 W[2][3][4];
#pragma unroll
            for (int g = 0; g < 3; ++g)
#pragma unroll
                for (int q = 0; q < 4; ++q)
                    W[0][g][q] = *(const s16x8*)(pW[g] + (size_t)q * 512);
#pragma unroll
            for (int bt = 0; bt < 8; ++bt) {
                if (bt < 7) {
#pragma unroll
                    for (int g = 0; g < 3; ++g)
#pragma unroll
                        for (int q = 0; q < 4; ++q)
                            W[(bt + 1) & 1][g][q] =
                                *(const s16x8*)(pW[g] + (size_t)((bt + 1) * 4 + q) * 512);
                }
#pragma unroll
                for (int q = 0; q < 4; ++q) {
                    s16x8 av = *(const s16x8*)&Al[(abase + (bt * 4 + q) * 32) ^ axor];
                    aR = __builtin_amdgcn_mfma_f32_16x16x32_bf16(av, W[bt & 1][0][q], aR, 0, 0, 0);
                    aZ = __builtin_amdgcn_mfma_f32_16x16x32_bf16(av, W[bt & 1][1][q], aZ, 0, 0, 0);
                    aN = __builtin_amdgcn_mfma_f32_16x16x32_bf16(av, W[bt & 1][2][q], aN, 0, 0, 0);
                }
            }
        }
#pragma unroll
        for (int r = 0; r < 4; ++r) {
            int b = brow + r;
            const u16* xr = xg + ((size_t)b * 100 + t) * 3072;
            float pr = bf2f((short)xr[jc]) + aR[r] + bhr;
            float pz = bf2f((short)xr[1024 + jc]) + aZ[r] + bhz;
            float pn = bf2f((short)xr[2048 + jc]);
            float rg = 1.f / (1.f + expf(-pr));
            float zg = 1.f / (1.f + expf(-pz));
            float ng = tanhf(pn + rg * (aN[r] + bhn));
            float hnew = (1.f - zg) * ng + zg * hold[r];
            hold[r] = hnew;
            OutE[((lane >> 4) * 4 + r) * 64 + wv * 16 + (lane & 15)] = f2bf(hnew);
        }
        __syncthreads();
        if (tid < 128) {     // coalesced cross-block + y stores (16 b x 64 j tile)
            int bl = tid >> 3, jl = (tid & 7) * 8;
            s16x8 v = *(const s16x8*)&OutE[bl * 64 + jl];
            const u64* pv = (const u64*)&v;
            u16* hw = hbf + (size_t)((t + 1) & 1) * 65536
                    + (size_t)(b0 + bl) * 1024 + jg * 64 + jl;
            coh_store_u64(hw, pv[0]);
            coh_store_u64(hw + 4, pv[1]);
            *(s16x8*)(y + ((size_t)(b0 + bl) * 100 + t) * 2048
                        + (size_t)dir * 1024 + jg * 64 + jl) = v;
        }
        if (t < 99) {
            __syncthreads();                           // drain h stores (vmcnt 0)
            if (tid == 0) flag_store(&flags[jg], (unsigned)(t + 1));
        }
    }
}

// ---------------- persistent decoder scan, H=K=2048 (R4-proven structure) ----------------
// 128 blocks x 256 threads = 32 jg x 4 bq. Central flag-array barrier (block-0 sweep,
// single epoch word) -- R6's per-consumer flag polling regressed 3.6x; reverted.
__global__ __launch_bounds__(256)
void dec_persist(const u16* __restrict__ Wp,    // packed [3][128][64] frags (bf16)
                 const float* __restrict__ db,  // [2][6144] fp32
                 const float* __restrict__ h32, // [64][2048] fp32 init (pp0)
                 u16* __restrict__ hbf,         // [2][64][2048] bf16 ping-pong
                 u16* __restrict__ ys,          // [6400][2048] bf16
                 unsigned* __restrict__ bar)
{
    __shared__ u16 Al[16 * 2048];                // 64 KB A-tile, XOR-swizzled
    __shared__ u16 OutD[16 * 64];                // 2 KB h-out staging
    const int tid = threadIdx.x;
    const int lane = tid & 63;
    const int wv = tid >> 6;
    const int xcd = blockIdx.x & 7;
    const int idx = blockIdx.x >> 3;                   // 0..15
    const int jg = xcd * 4 + (idx & 3);                // 32 j-groups of 64
    const int b0 = (idx >> 2) * 16;                    // 4 batch quarters
    const int jc = jg * 64 + wv * 16 + (lane & 15);
    const int jt = jg * 4 + wv;                        // packed j-tile (JT=128, KB=64)
    const int kq = (lane >> 4) * 8;
    const int arow = lane & 15;
    const int axor = (arow & 7) << 3;
    const float gir = db[jc]        + db[6144 + jc];
    const float giz = db[2048 + jc] + db[8192 + jc];
    const float gin = db[4096 + jc];
    const float bhn = db[10240 + jc];
    const u16* pR = Wp + ((size_t)(0 * 128 + jt) * 64) * 512 + lane * 8;
    const u16* pZ = Wp + ((size_t)(1 * 128 + jt) * 64) * 512 + lane * 8;
    const u16* pN = Wp + ((size_t)(2 * 128 + jt) * 64) * 512 + lane * 8;
    f4v hold;
#pragma unroll
    for (int r = 0; r < 4; ++r)
        hold[r] = h32[(size_t)(b0 + (lane >> 4) * 4 + r) * 2048 + jc];

    for (int t = 0; t < 100; ++t) {
        // stage 16 rows x 2048 (64 KB): 4096 chunks, two 16-deep bursts
        const u16* hb = hbf + (size_t)(t & 1) * 131072 + (size_t)b0 * 2048;
#pragma unroll
        for (int h = 0; h < 2; ++h) {
            u64 tmp[16];
#pragma unroll
            for (int g = 0; g < 8; ++g) {
                int c = tid + (h * 8 + g) * 256;
                const u16* gp = hb + (size_t)(c >> 8) * 2048 + (c & 255) * 8;
                tmp[2 * g]     = coh_load_u64(gp);
                tmp[2 * g + 1] = coh_load_u64(gp + 4);
            }
#pragma unroll
            for (int g = 0; g < 8; ++g) {
                int c = tid + (h * 8 + g) * 256;
                int di = (c * 8) ^ (((c >> 8) & 7) << 3);
                *(u64*)&Al[di]     = tmp[2 * g];
                *(u64*)&Al[di + 4] = tmp[2 * g + 1];
            }
        }
        __syncthreads();
        f4v aR = {0.f, 0.f, 0.f, 0.f}, aZ = aR, aN = aR;
        const int abase = arow * 2048 + kq;
        s16x8 cR = *(const s16x8*)(pR);
        s16x8 cZ = *(const s16x8*)(pZ);
        s16x8 cN = *(const s16x8*)(pN);
        for (int kb = 0; kb < 64; ++kb) {
            int kn = (kb + 1 < 64) ? kb + 1 : kb;
            s16x8 nR = *(const s16x8*)(pR + (size_t)kn * 512);
            s16x8 nZ = *(const s16x8*)(pZ + (size_t)kn * 512);
            s16x8 nN = *(const s16x8*)(pN + (size_t)kn * 512);
            s16x8 av = *(const s16x8*)&Al[(abase + kb * 32) ^ axor];
            aR = __builtin_amdgcn_mfma_f32_16x16x32_bf16(av, cR, aR, 0, 0, 0);
            aZ = __builtin_amdgcn_mfma_f32_16x16x32_bf16(av, cZ, aZ, 0, 0, 0);
            aN = __builtin_amdgcn_mfma_f32_16x16x32_bf16(av, cN, aN, 0, 0, 0);
            cR = nR; cZ = nZ; cN = nN;
        }
        __syncthreads();     // Al done being read; OutD region reuse safe
#pragma unroll
        for (int r = 0; r < 4; ++r) {
            float pr = gir + aR[r];
            float pz = giz + aZ[r];
            float rg = 1.f / (1.f + expf(-pr));
            float zg = 1.f / (1.f + expf(-pz));
            float ng = tanhf(gin + rg * (aN[r] + bhn));
            float hnew = (1.f - zg) * ng + zg * hold[r];
            hold[r] = hnew;
            OutD[((lane >> 4) * 4 + r) * 64 + wv * 16 + (lane & 15)] = f2bf(hnew);
        }
        __syncthreads();
        if (tid < 128) {     // coalesced cross-block + ys stores (16 b x 64 j tile)
            int bl = tid >> 3, jl = (tid & 7) * 8;
            s16x8 v = *(const s16x8*)&OutD[bl * 64 + jl];
            const u64* pv = (const u64*)&v;
            u16* hw = hbf + (size_t)((t + 1) & 1) * 131072
                    + (size_t)(b0 + bl) * 2048 + jg * 64 + jl;
            coh_store_u64(hw, pv[0]);
            coh_store_u64(hw + 4, pv[1]);
            *(s16x8*)(ys + ((size_t)(b0 + bl) * 100 + t) * 2048 + jg * 64 + jl) = v;
        }
        if (t < 99) flag_barrier(bar, 128, (unsigned)(t + 1));
    }
}

// ---------------- gather enc_hidden = y[b, sl-1]; init decoder h ----------------
__global__ __launch_bounds__(256)
void gather_kernel(const int* __restrict__ seq_len, const u16* __restrict__ y,
                   float* __restrict__ out_enc, float* __restrict__ h32d,
                   u16* __restrict__ hbfd)
{
    int idx = blockIdx.x * 256 + threadIdx.x;   // < 131072
    int b = idx >> 11, j = idx & 2047;
    int s = seq_len[b];
    s = s < 1 ? 1 : (s > 100 ? 100 : s);
    u16 v = y[((size_t)b * 100 + (s - 1)) * 2048 + j];
    float f = bf2f((short)v);
    out_enc[idx] = f;
    h32d[idx] = f;     // pp0
    hbfd[idx] = v;     // pp0
}

// ---------------- output projection: dec_out[6400,75] = ys @ out_W^T + out_b ----------------
__global__ __launch_bounds__(256)
void proj_kernel(const u16* __restrict__ ys, const float* __restrict__ oW,
                 const float* __restrict__ oB, float* __restrict__ dec_out)
{
    const int r0 = blockIdx.x * 8;   // 800 blocks
    __shared__ float yl[8][2048];
    __shared__ float psum[3][8][76];
    for (int idx = threadIdx.x; idx < 2048; idx += 256) {
        int rr = idx >> 8, cc = idx & 255;
        s16x8 v = ((const s16x8*)(ys + (size_t)(r0 + rr) * 2048))[cc];
#pragma unroll
        for (int i = 0; i < 8; ++i) yl[rr][cc * 8 + i] = bf2f(v[i]);
    }
    __syncthreads();
    if (threadIdx.x < 225) {
        int d = threadIdx.x % 75, seg = threadIdx.x / 75;
        int ks = seg * 683, ke = ks + 683 < 2048 ? ks + 683 : 2048;
        const float* wr = oW + (size_t)d * 2048;
        float acc[8] = {0.f, 0.f, 0.f, 0.f, 0.f, 0.f, 0.f, 0.f};
        for (int k = ks; k < ke; ++k) {
            float w = wr[k];
#pragma unroll
            for (int r = 0; r < 8; ++r) acc[r] += yl[r][k] * w;
        }
#pragma unroll
        for (int r = 0; r < 8; ++r) psum[seg][r][d] = acc[r];
    }
    __syncthreads();
    for (int idx = threadIdx.x; idx < 600; idx += 256) {
        int r = idx / 75, d = idx % 75;
        dec_out[(size_t)(r0 + r) * 75 + d] =
            psum[0][r][d] + psum[1][r][d] + psum[2][r][d] + oB[d];
    }
}

// ================== fallback kernels (small-ws path) ==================
__device__ __forceinline__ void gemv3_f32(const float* __restrict__ w0,
                                          const float* __restrict__ w1,
                                          const float* __restrict__ w2,
                                          const f4v* __restrict__ hv,
                                          int n4, float& a0, float& a1, float& a2)
{
    for (int k = 0; k < n4; ++k) {
        f4v h4 = hv[k];
        f4v x0 = *(const f4v*)(w0 + k * 4);
        f4v x1 = *(const f4v*)(w1 + k * 4);
        f4v x2 = *(const f4v*)(w2 + k * 4);
        a0 += h4[0]*x0[0] + h4[1]*x0[1] + h4[2]*x0[2] + h4[3]*x0[3];
        a1 += h4[0]*x1[0] + h4[1]*x1[1] + h4[2]*x1[2] + h4[3]*x1[3];
        a2 += h4[0]*x2[0] + h4[1]*x2[1] + h4[2]*x2[2] + h4[3]*x2[3];
    }
}
__device__ __forceinline__ float dot_w32_v32(const float* __restrict__ w,
                                             const float* __restrict__ v, int n)
{
    float a = 0.f;
    for (int k = 0; k < n; ++k) a += w[k] * v[k];
    return a;
}
__device__ __forceinline__ float dot_w32_vbf(const float* __restrict__ w,
                                             const u16* __restrict__ v, int n8)
{
    float a = 0.f;
    for (int k8 = 0; k8 < n8; ++k8) {
        s16x8 v8 = *(const s16x8*)(v + k8 * 8);
        f4v w0 = *(const f4v*)(w + k8 * 8);
        f4v w1 = *(const f4v*)(w + k8 * 8 + 4);
        a += w0[0]*bf2f(v8[0]) + w0[1]*bf2f(v8[1]) + w0[2]*bf2f(v8[2]) + w0[3]*bf2f(v8[3])
           + w1[0]*bf2f(v8[4]) + w1[1]*bf2f(v8[5]) + w1[2]*bf2f(v8[6]) + w1[3]*bf2f(v8[7]);
    }
    return a;
}

__global__ __launch_bounds__(512)
void enc_scan_fused(int t,
                    const float* __restrict__ h_in, float* __restrict__ h_out,
                    const float* __restrict__ Whh, size_t whh_stride,
                    const float* __restrict__ Wih, size_t wih_stride, int Kin,
                    const float* __restrict__ xf, const u16* __restrict__ xb,
                    const float* __restrict__ bias, int bias_stride,
                    u16* __restrict__ y)
{
    const int dir = blockIdx.z;
    const int jt = blockIdx.x;
    const int b0 = blockIdx.y * 16;
    __shared__ float hlds[16][1024];
    const float* hin = h_in + (size_t)dir * 65536 + (size_t)b0 * 1024;
    if (t == 0) {
        f4v z = {0.f, 0.f, 0.f, 0.f};
        for (int idx = threadIdx.x; idx < 4096; idx += 512) ((f4v*)hlds)[idx] = z;
    } else {
        for (int idx = threadIdx.x; idx < 4096; idx += 512)
            ((f4v*)hlds)[idx] = ((const f4v*)hin)[idx];
    }
    __syncthreads();
    const int jl = threadIdx.x & 31;
    const int j  = jt * 32 + jl;
    const int bp = threadIdx.x >> 5;
    const float* wd = Whh + (size_t)dir * whh_stride;
    float a0 = 0.f, a1 = 0.f, a2 = 0.f;
    gemv3_f32(wd + (size_t)j * 1024, wd + (size_t)(1024 + j) * 1024,
              wd + (size_t)(2048 + j) * 1024, (const f4v*)&hlds[bp][0], 256, a0, a1, a2);
    const float* bd = bias + dir * bias_stride;
    const float* wi = Wih + (size_t)dir * wih_stride;
    const int gb = b0 + bp;
    float gi[3];
#pragma unroll
    for (int g = 0; g < 3; ++g) {
        const float* wr = wi + (size_t)(g * 1024 + j) * Kin;
        float s;
        if (xf) s = dot_w32_v32(wr, xf + ((size_t)gb * 100 + t) * Kin, Kin);
        else    s = dot_w32_vbf(wr, xb + ((size_t)gb * 100 + t) * Kin, Kin >> 3);
        gi[g] = bd[g * 1024 + j] + s;
    }
    const float* bhh = bd + 3072;
    float pr = gi[0] + a0 + bhh[j];
    float pz = gi[1] + a1 + bhh[1024 + j];
    float rg = 1.f / (1.f + expf(-pr));
    float zg = 1.f / (1.f + expf(-pz));
    float ng = tanhf(gi[2] + rg * (a2 + bhh[2048 + j]));
    float hold = hlds[bp][j];
    float hnew = (1.f - zg) * ng + zg * hold;
    h_out[(size_t)dir * 65536 + (size_t)gb * 1024 + j] = hnew;
    y[((size_t)gb * 100 + t) * 2048 + (size_t)dir * 1024 + j] = f2bf(hnew);
}

__global__ __launch_bounds__(512)
void dec_scan_step(int t, const float* __restrict__ h_in, float* __restrict__ h_out,
                   const float* __restrict__ Whh, const float* __restrict__ db,
                   u16* __restrict__ ys)
{
    const int jt = blockIdx.x;
    const int b0 = blockIdx.y * 16;
    __shared__ float hlds[16][1024];
    const int jl = threadIdx.x & 31;
    const int j  = jt * 32 + jl;
    const int bp = threadIdx.x >> 5;
    float a0 = 0.f, a1 = 0.f, a2 = 0.f;
    float hold = 0.f;
    for (int kc = 0; kc < 2; ++kc) {
        for (int idx = threadIdx.x; idx < 4096; idx += 512) {
            int rr = idx >> 8, cc = idx & 255;
            ((f4v*)hlds)[idx] = *(const f4v*)(h_in + (size_t)(b0 + rr) * 2048 + kc * 1024 + cc * 4);
        }
        __syncthreads();
        if ((j >> 10) == kc) hold = hlds[bp][j & 1023];
        const float* wb = Whh + kc * 1024;
        gemv3_f32(wb + (size_t)j * 2048, wb + (size_t)(2048 + j) * 2048,
                  wb + (size_t)(4096 + j) * 2048, (const f4v*)&hlds[bp][0], 256, a0, a1, a2);
        __syncthreads();
    }
    const int gb = b0 + bp;
    float pr = db[j] + a0 + db[6144 + j];
    float pz = db[2048 + j] + a1 + db[6144 + 2048 + j];
    float rg = 1.f / (1.f + expf(-pr));
    float zg = 1.f / (1.f + expf(-pz));
    float ng = tanhf(db[4096 + j] + rg * (a2 + db[6144 + 4096 + j]));
    float hnew = (1.f - zg) * ng + zg * hold;
    h_out[(size_t)gb * 2048 + j] = hnew;
    ys[((size_t)gb * 100 + t) * 2048 + j] = f2bf(hnew);
}

// ============================ launcher ============================
extern "C" void kernel_launch(void* const* d_in, const int* in_sizes, int n_in,
                              void* d_out, int out_size, void* d_ws, size_t ws_size,
                              hipStream_t stream)
{
    const float* x    = (const float*)d_in[0];
    const int*   sl   = (const int*)d_in[1];
    const float* Wih0 = (const float*)d_in[2];
    const float* Whh0 = (const float*)d_in[3];
    const float* b0   = (const float*)d_in[4];
    const float* Wih  = (const float*)d_in[5];
    const float* Whh  = (const float*)d_in[6];
    const float* bE   = (const float*)d_in[7];
    const float* dWhh = (const float*)d_in[9];
    const float* dB   = (const float*)d_in[10];
    const float* oW   = (const float*)d_in[11];
    const float* oB   = (const float*)d_in[12];
    float* out_enc = (float*)d_out;            // [64][2048]
    float* dec_out = (float*)d_out + 131072;   // [64][100][75]

    char* ws = (char*)d_ws;
    // ---- persistent-path layout ----
    const size_t XG_OFF   = 0;            // [6400][3072] bf16 (one dir): 39,321,600
    const size_t YA_OFF   = 39321600;     // [6400][2048] bf16: 26,214,400
    const size_t YB_OFF   = 65536000;     // [6400][2048] bf16
    const size_t WC_OFF   = 91750400;     // packed enc W bf16: 6,291,456
    const size_t HBFE_OFF = 98566144;     // [2][64][1024] bf16: 262,144
    const size_t H32D_OFF = 98828288;     // [2][64][2048] f32: 1,048,576
    const size_t HBFD_OFF = 99876864;     // [2][64][2048] bf16: 524,288
    const size_t BAR_OFF  = 100401152;    // 7 slots x 1 KB
    const size_t NEED     = 100408320;

    dim3 blk256(256), blk512(512);

    if (ws_size >= NEED) {
        u16*   xg   = (u16*)(ws + XG_OFF);
        u16*   y_a  = (u16*)(ws + YA_OFF);
        u16*   y_b  = (u16*)(ws + YB_OFF);
        u16*   Wc   = (u16*)(ws + WC_OFF);
        u16*   hbfE = (u16*)(ws + HBFE_OFF);
        float* h32D = (float*)(ws + H32D_OFF);
        u16*   hbfD = (u16*)(ws + HBFD_OFF);
        unsigned* bar = (unsigned*)(ws + BAR_OFF);

        zero_bar<<<dim3(7), blk256, 0, stream>>>(bar, 1792);

        int slot = 0;
        for (int l = 0; l < 3; ++l) {
            const u16* y_in = (l == 0) ? (const u16*)0 : ((l == 1) ? y_a : y_b);
            u16* y_out      = (l == 2) ? y_a : ((l == 0) ? y_a : y_b);
            for (int d = 0; d < 2; ++d) {
                const float* Wsrc = (l == 0) ? (Whh0 + (size_t)d * 3145728)
                                             : (Whh + ((size_t)(l - 1) * 2 + d) * 3145728);
                const float* bias = (l == 0) ? (b0 + (size_t)d * 6144)
                                             : (bE + (size_t)(l - 1) * 12288 + (size_t)d * 6144);
                cvt_pack<<<dim3(1536), blk256, 0, stream>>>(Wsrc, Wc, 64, 32, 1024);
                if (l == 0)
                    xg0_kernel<<<dim3(400), blk256, 0, stream>>>(
                        x, Wih0 + (size_t)d * 230400, b0 + (size_t)d * 6144, xg);
                else
                    xg_gemm2<<<dim3(2400), blk256, 0, stream>>>(
                        y_in, Wih + ((size_t)(l - 1) * 2 + d) * 6291456, bias, xg, 2048);
                enc_persist<<<dim3(64), blk256, 0, stream>>>(
                    Wc, bias, xg, hbfE, y_out, d, bar + (size_t)slot * 256);
                ++slot;
            }
        }
        gather_kernel<<<dim3(512), blk256, 0, stream>>>(sl, y_a, out_enc, h32D, hbfD);
        u16* decW = (u16*)(ws + XG_OFF);   // reuse xg region (25.2 MB needed)
        cvt_pack<<<dim3(6144), blk256, 0, stream>>>(dWhh, decW, 128, 64, 2048);
        dec_persist<<<dim3(128), blk256, 0, stream>>>(decW, dB, h32D, hbfD, y_b,
                                                      bar + (size_t)6 * 256);
        proj_kernel<<<dim3(800), blk256, 0, stream>>>(y_b, oW, oB, dec_out);
    } else {
        // ---- fallback: fused path (~55 MiB) ----
        const size_t Y_B = 26214400;
        u16*   y_a  = (u16*)ws;
        u16*   y_b  = (u16*)(ws + Y_B);
        float* hE   = (float*)(ws + 2 * Y_B);                 // [2][2][64][1024] f32: 1 MB
        float* h32D = (float*)(ws + 2 * Y_B + 1048576);       // [2][64][2048] f32: 1 MB
        u16*   hbfD = (u16*)(ws + 2 * Y_B + 2097152);         // 0.5 MB

        for (int t = 0; t < 100; ++t) {
            int pp = t & 1;
            enc_scan_fused<<<dim3(32, 4, 2), blk512, 0, stream>>>(
                t, hE + (size_t)pp * 131072, hE + (size_t)(pp ^ 1) * 131072,
                Whh0, (size_t)3145728, Wih0, (size_t)230400, 75, x, (const u16*)0,
                b0, 6144, y_a);
        }
        for (int l = 0; l < 2; ++l) {
            const u16* yin = (l == 0) ? y_a : y_b;
            u16* yout      = (l == 0) ? y_b : y_a;
            for (int t = 0; t < 100; ++t) {
                int pp = t & 1;
                enc_scan_fused<<<dim3(32, 4, 2), blk512, 0, stream>>>(
                    t, hE + (size_t)pp * 131072, hE + (size_t)(pp ^ 1) * 131072,
                    Whh + (size_t)l * 2 * 3145728, (size_t)3145728,
                    Wih + (size_t)l * 2 * 6291456, (size_t)6291456, 2048,
                    (const float*)0, yin, bE + (size_t)l * 12288, 6144, yout);
            }
        }
        gather_kernel<<<dim3(512), blk256, 0, stream>>>(sl, y_a, out_enc, h32D, hbfD);
        for (int t = 0; t < 100; ++t) {
            int pp = t & 1;
            dec_scan_step<<<dim3(64, 4), blk512, 0, stream>>>(
                t, h32D + (size_t)pp * 131072, h32D + (size_t)(pp ^ 1) * 131072, dWhh, dB, y_b);
        }
        proj_kernel<<<dim3(800), blk256, 0, stream>>>(y_b, oW, oB, dec_out);
    }
}